// Round 10
// baseline (131.137 us; speedup 1.0000x reference)
//
#include <hip/hip_runtime.h>

// ConvT3d(32->16,k3,s2,p1)+BN+4^3 avgpool, bf16 MFMA.
// R15: VALU micro-cuts on the R14 structure (R14: convf2 dropped below the
// harness fill floor, ~<=40us; counters hidden). Two changes only:
//  1) packed-f32 epilogue: v_pk_add_f32 / v_pk_fma_f32 (full-rate 2xf32 on
//     CDNA, hipcc never auto-emits) accumulate {a0,a1}/{a2,a3} vreg pairs:
//     interior epilogue 64 -> ~39 inst. Same values (pairwise reassoc).
//  2) immediate-offset LDS addressing: LDA/LDB = thread-invariant base ptr
//     + compile-time byte offset -> single ds_read_b128 with offset:imm,
//     zero per-call VALU (only di*3168 once per PH).
// Everything else frozen = R14: 512 thr, wave odq owns od (m=odq>>1; even:
// kd=1 di=m; odd: kd=2 di=m + kd=0 di=m+1), bias closed-form fold, fast/
// edge epilogue split, wT once/block via zero-VGPR global_load_lds, x via
// 9(5/4) float4 + in-reg transpose, launch_bounds(512,6), LDS 51.8KB.
// kh-pair: kh0:(hi1,oh1),(hi2,oh3); kh1:(hi0,oh0),(hi1,oh2);
//          kh2:(hi0,oh1),(hi1,oh3)   (validated R1-R14)

typedef __attribute__((ext_vector_type(8))) short bf16x8;
typedef __attribute__((ext_vector_type(4))) float f32x4;
typedef __attribute__((ext_vector_type(2))) float f32x2;

static __device__ __forceinline__ unsigned short f2bf(float f) {
    unsigned int u = __float_as_uint(f);
    u = (u + 0x7fffu + ((u >> 16) & 1u)) >> 16;   // RNE
    return (unsigned short)u;
}
static __device__ __forceinline__ unsigned cvtpk(float a, float b) {
    unsigned r;
    asm("v_cvt_pk_bf16_f32 %0, %1, %2" : "=v"(r) : "v"(a), "v"(b));
    return r;
}
static __device__ __forceinline__ void pkadd(f32x2& acc, f32x2 a) {
    asm("v_pk_add_f32 %0, %1, %0" : "+v"(acc) : "v"(a));
}
static __device__ __forceinline__ void pkfma(f32x2& acc, f32x2 a) {
    asm("v_pk_fma_f32 %0, %1, %1, %0" : "+v"(acc) : "v"(a));
}

// ---- w convert: w[ci][co][tap] fp32 -> wT[tap][co][ci] bf16 (tap=kd*9+kh*3+kw)
__global__ __launch_bounds__(256)
void kw(const float* __restrict__ w, unsigned short* __restrict__ wT)
{
    const int idx = blockIdx.x * 256 + threadIdx.x;
    if (idx < 13824) {
        const int ci = idx & 31, co = (idx >> 5) & 15, tap = idx >> 9;
        wT[idx] = f2bf(w[(ci * 16 + co) * 27 + tap]);
    }
}

// ---- fused stage + convT + BN-stats + pool partials, 512 threads
__global__ __launch_bounds__(512, 6)
void convf2(const float* __restrict__ x,
            const unsigned short* __restrict__ wT,
            const float* __restrict__ bias,
            float* __restrict__ pooled,
            float* __restrict__ psum, float* __restrict__ psq)
{
    const int ht = blockIdx.x, dt = blockIdx.y, n = blockIdx.z;
    const int tid = threadIdx.x;
    const int vv = tid >> 6, lane = tid & 63;   // wave 0..7
    const int tw = vv & 1, odq = vv >> 1;       // ow half / od index
    const int c = lane & 15, qd = lane >> 4;    // co / K-granule

    __shared__ alignas(16) unsigned short xs[9504];    // 19008 B
    __shared__ alignas(16) unsigned short wTs[13824];  // 27648 B
    __shared__ float sred[8][16], qred[8][16], pbuf[4][2][8][16];

    const float bv = bias[c];                   // one 4B load, L1-resident

    // ---- stage wT -> LDS, zero VGPR (27 x 1KB chunks over 8 waves)
    #pragma unroll
    for (int i = 0; i < 4; ++i) {
        const int chunk = vv + 8 * i;           // wave-uniform
        if (chunk < 27) {
            __builtin_amdgcn_global_load_lds(
                (const char*)wT + chunk * 1024 + lane * 16,
                (char*)wTs + chunk * 1024,
                16, 0, 0);
        }
    }

    // ---- stage x: half h = tid>>8 covers planes p = 2i+h (5 / 4 planes)
    const int h = tid >> 8, ltid = tid & 255;
    const int ciS = ltid >> 3, q = ltid & 7;
    const int oL = ciS & 7;
    const int g = ciS >> 3;
    const float* xbase = x + (size_t)(n*32 + ciS)*32768 + 4*q;
    float4 F[5];
    #pragma unroll
    for (int i = 0; i < 5; ++i) {
        const int p = 2*i + h;
        if (p < 9) {
            const int di = p / 3, hp = p - 3*(p/3);
            const int id = 2*dt + di, ih = 2*ht + hp;
            F[i] = (id < 32 && ih < 32)
                 ? *(const float4*)(xbase + id*1024 + ih*32)
                 : make_float4(0.f, 0.f, 0.f, 0.f);
        }
    }
    const unsigned selP = (lane & 8) ? 0x07060302u : 0x01000504u;
    const int iwT = 4*q + (oL & 3), hT = oL >> 2;
    #pragma unroll
    for (int i = 0; i < 5; ++i) {
        const int p = 2*i + h;
        if (p < 9) {
            unsigned u0 = cvtpk(F[i].x, F[i].y);
            unsigned u1 = cvtpk(F[i].z, F[i].w);
            const unsigned a0 = (unsigned)__shfl_xor((int)u0, 8, 64);
            const unsigned a1 = (unsigned)__shfl_xor((int)u1, 8, 64);
            u0 = __builtin_amdgcn_perm(u0, a0, selP);
            u1 = __builtin_amdgcn_perm(u1, a1, selP);
            const unsigned s0 = (unsigned)__shfl_xor((int)u0, 16, 64);
            const unsigned s1 = (unsigned)__shfl_xor((int)u1, 16, 64);
            const unsigned w0 = (lane & 16) ? s1 : u0;
            const unsigned w1 = (lane & 16) ? u1 : s0;
            *(uint2*)(xs + p*1056 + g*264 + iwT*8 + 4*hT) = make_uint2(w0, w1);
        }
    }
    if (tid < 36) {
        const int dihi = tid >> 2, gg = tid & 3;
        *(uint4*)(xs + dihi*1056 + gg*264 + 256) = make_uint4(0,0,0,0);
    }

    __syncthreads();   // drains vmcnt -> wTs + xs ready

    // ---- compute: wave owns od = odq
    f32x4 acc[4][2];   // [oh][par]
    #pragma unroll
    for (int oh = 0; oh < 4; ++oh)
        #pragma unroll
        for (int par = 0; par < 2; ++par)
            acc[oh][par] = (f32x4){0.f,0.f,0.f,0.f};

    const int iwb = 16 * tw + c;
    // thread-invariant LDS base pointers; all per-access offsets are
    // compile-time -> ds_read_b128 with offset:imm, zero per-call VALU.
    const unsigned short* Abase = xs + qd*264 + iwb*8;
    const unsigned short* Bbase = wTs + c*32 + qd*8;

    constexpr int KHP[3][2][2] = {
        {{1,1},{2,3}},   // kh0
        {{0,0},{1,2}},   // kh1
        {{0,1},{1,3}},   // kh2
    };
    auto PH = [&](int tapbase, int di) {
        const unsigned short* Ab = Abase + di * 3168;   // one mul per PH
        #pragma unroll
        for (int kh = 0; kh < 3; ++kh) {
            const bf16x8 B0 = *(const bf16x8*)(Bbase + (tapbase + kh*3 + 0)*512);
            const bf16x8 B1 = *(const bf16x8*)(Bbase + (tapbase + kh*3 + 1)*512);
            const bf16x8 B2 = *(const bf16x8*)(Bbase + (tapbase + kh*3 + 2)*512);
            #pragma unroll
            for (int pp = 0; pp < 2; ++pp) {
                const int hi = KHP[kh][pp][0], oh = KHP[kh][pp][1];
                const bf16x8 A0 = *(const bf16x8*)(Ab + hi*1056);
                const bf16x8 A1 = *(const bf16x8*)(Ab + hi*1056 + 8);
                acc[oh][0] = __builtin_amdgcn_mfma_f32_16x16x32_bf16(
                    A0, B1, acc[oh][0], 0, 0, 0);
                acc[oh][1] = __builtin_amdgcn_mfma_f32_16x16x32_bf16(
                    A1, B0, acc[oh][1], 0, 0, 0);
                acc[oh][1] = __builtin_amdgcn_mfma_f32_16x16x32_bf16(
                    A0, B2, acc[oh][1], 0, 0, 0);
            }
        }
    };
    const int m = odq >> 1;
    if ((odq & 1) == 0) {
        PH(9, m);                 // even od=2m: kd=1, di=m
    } else {
        PH(18, m);                // odd od=2m+1: kd=2, di=m
        PH(0,  m + 1);            //              kd=0, di=m+1
    }

    // ---- epilogue on RAW acc (packed-f32 fast path)
    const bool inter = (dt < 15) && (ht < 15);
    const bool owx = (tw == 1) && (qd == 3);    // this thread holds ow==63
    float s_raw, sq_raw, cnt;
    float P0 = 0.f, P1 = 0.f;
    if (inter) {
        f32x2 Pa = (f32x2){0.f,0.f}, Pb = (f32x2){0.f,0.f};
        f32x2 Qa = (f32x2){0.f,0.f}, Qb = (f32x2){0.f,0.f};
        #pragma unroll
        for (int oh = 0; oh < 4; ++oh)
            #pragma unroll
            for (int par = 0; par < 2; ++par) {
                const f32x4 a = acc[oh][par];
                const f32x2 lo = (f32x2){a[0], a[1]};
                const f32x2 hi = (f32x2){a[2], a[3]};
                pkadd(Pa, lo); pkfma(Qa, lo);
                pkadd(Pb, hi); pkfma(Qb, hi);
            }
        P0 = Pa[0] + Pa[1];
        P1 = Pb[0] + Pb[1];
        float sqr = (Qa[0] + Qa[1]) + (Qb[0] + Qb[1]);
        float corr = 0.f, corrq = 0.f;
        if (owx) {                               // remove ow==63 (par1,r3)
            #pragma unroll
            for (int oh = 0; oh < 4; ++oh) {
                const float a = acc[oh][1][3];
                corr += a; corrq = fmaf(a, a, corrq);
            }
        }
        s_raw  = (P0 + P1) - corr;
        sq_raw = sqr - corrq;
        cnt    = owx ? 28.f : 32.f;
    } else {
        s_raw = 0.f; sq_raw = 0.f; cnt = 0.f;
        const bool odok = !(dt == 15 && odq == 3);
        #pragma unroll
        for (int oh = 0; oh < 4; ++oh) {
            const bool ohok = !(ht == 15 && oh == 3);
            #pragma unroll
            for (int par = 0; par < 2; ++par)
                #pragma unroll
                for (int r = 0; r < 4; ++r) {
                    const float a = acc[oh][par][r];
                    const bool owok = !(par == 1 && owx && r == 3);
                    const float mk = (odok && ohok && owok) ? 1.f : 0.f;
                    const float t = mk * a;
                    s_raw += t; sq_raw = fmaf(t, a, sq_raw); cnt += mk;
                    P0 += (r < 2) ? t : 0.f;     // keep P defs consistent
                    P1 += (r >= 2) ? t : 0.f;
                }
        }
        // edge blocks don't write pooled (inter==false), P values unused
    }
    // biased sums via closed form
    float s_b  = fmaf(cnt, bv, s_raw);
    float sq_b = fmaf(fmaf(cnt, bv, 2.f * s_raw), bv, sq_raw);

    s_b  += __shfl_xor(s_b, 16, 64);  s_b  += __shfl_xor(s_b, 32, 64);
    sq_b += __shfl_xor(sq_b, 16, 64); sq_b += __shfl_xor(sq_b, 32, 64);
    if (lane < 16) { sred[vv][lane] = s_b; qred[vv][lane] = sq_b; }
    pbuf[odq][tw][2*qd + 0][c] = P0;
    pbuf[odq][tw][2*qd + 1][c] = P1;

    __syncthreads();

    if (tid < 16) {
        const int blk = (n*16 + dt)*16 + ht;
        float S = 0.f, Q = 0.f;
        #pragma unroll
        for (int wv = 0; wv < 8; ++wv) { S += sred[wv][tid]; Q += qred[wv][tid]; }
        psum[tid*4096 + blk] = S;
        psq [tid*4096 + blk] = Q;
    }
    if (odq == 3 && inter) {                     // pool: sum 4 od partials (RAW)
        #pragma unroll
        for (int jj = 0; jj < 2; ++jj) {
            const int jl = 2*qd + jj, jg = 8*tw + jl;
            if (jg < 15) {
                const float tot = pbuf[0][tw][jl][c] + pbuf[1][tw][jl][c]
                                + pbuf[2][tw][jl][c] + pbuf[3][tw][jl][c];
                pooled[(n*16 + c)*3375 + dt*225 + ht*15 + jg] = tot * (1.f/64.f);
            }
        }
    }
}

__global__ void bnfinal(const float* __restrict__ psum, const float* __restrict__ psq,
                        const float* __restrict__ gamma, const float* __restrict__ beta,
                        const float* __restrict__ bias,
                        float* __restrict__ bn)
{
    const int co = blockIdx.x;
    const int t  = threadIdx.x;
    float S = 0, Q = 0;
    for (int blk = t; blk < 4096; blk += 256) {
        S += psum[co*4096 + blk];
        Q += psq [co*4096 + blk];
    }
    #pragma unroll
    for (int off = 32; off > 0; off >>= 1) {
        S += __shfl_down(S, off, 64);
        Q += __shfl_down(Q, off, 64);
    }
    __shared__ float rs[4], rq[4];
    if ((t & 63) == 0) { rs[t >> 6] = S; rq[t >> 6] = Q; }
    __syncthreads();
    if (t == 0) {
        S = rs[0] + rs[1] + rs[2] + rs[3];
        Q = rq[0] + rq[1] + rq[2] + rq[3];
        const float cnt = 16.f * 63.f * 63.f * 63.f;
        const float mean = S / cnt;
        const float var  = Q / cnt - mean * mean;
        const float inv  = rsqrtf(var + 1e-5f);
        const float sc   = inv * gamma[co];
        bn[co]      = sc;
        // pooled stores RAW conv mean; bias enters the affine offset
        bn[16 + co] = beta[co] + (bias[co] - mean) * sc;
    }
}

__global__ void finalize(const float* __restrict__ pooled, const float* __restrict__ bn,
                         float* __restrict__ out)
{
    const int i  = blockIdx.x * 256 + threadIdx.x;   // 864000 = 3375*256
    const int co = (i / 3375) & 15;
    out[i] = pooled[i] * bn[co] + bn[16 + co];
}

extern "C" void kernel_launch(void* const* d_in, const int* in_sizes, int n_in,
                              void* d_out, int out_size, void* d_ws, size_t ws_size,
                              hipStream_t stream)
{
    const float* x     = (const float*)d_in[0];
    const float* w     = (const float*)d_in[1];
    const float* b     = (const float*)d_in[2];
    const float* gamma = (const float*)d_in[3];
    const float* beta  = (const float*)d_in[4];
    float* out = (float*)d_out;

    char* wsb = (char*)d_ws;
    unsigned short* wT = (unsigned short*)wsb;        // 27,648 B
    float* pooled = (float*)(wsb + 27648);            // 3,456,000 B
    float* psum   = (float*)(wsb + 27648 + 3456000);  // 262,144 B
    float* psq    = (float*)(wsb + 27648 + 3456000 + 262144);
    float* bn     = (float*)(wsb + 27648 + 3456000 + 2*262144);

    kw<<<54, 256, 0, stream>>>(w, wT);
    dim3 grid(16, 16, 16);   // (ht, dt, n)
    convf2<<<grid, 512, 0, stream>>>(x, wT, b, pooled, psum, psq);
    bnfinal<<<16, 256, 0, stream>>>(psum, psq, gamma, beta, b, bn);
    finalize<<<3375, 256, 0, stream>>>(pooled, bn, out);
}

// Round 11
// 130.463 us; speedup vs baseline: 1.0052x; 1.0052x over previous
//
#include <hip/hip_runtime.h>

// ConvT3d(32->16,k3,s2,p1)+BN+4^3 avgpool, bf16 MFMA.
// R16: LDS bank-conflict fix on B-reads. Evidence: SQ_LDS_BANK_CONFLICT
// 840K -> 4.4M exactly when wT moved to LDS (R10); LDB lane addr c*64+qd*16
// has addr%128 = (c&1)*64 within a 16-lane phase -> 8 lanes per 16B window
// = 8-way serialization (~2.9x, m136) on every B ds_read_b128. LDA is
// 16*((c+qd)&7) = 2-way = free (matches small pre-R10 baseline).
// Fix: XOR-swizzle wT at PRODUCTION (kw): granule slot s = (ci>>3) ^
// ((co>>1)&3). wTs is a linear global_load_lds copy -> LDS inherits the
// swizzle free. Reader compensates in the thread-invariant base only:
// Bbase = wTs + c*32 + (qd^((c>>1)&3))*8 -> hot-loop ds_read offsets
// byte-identical; new map = 2 lanes/window = free.
// Everything else frozen = R15: 512 thr, wave odq owns od (m=odq>>1; even:
// kd=1 di=m; odd: kd=2 di=m + kd=0 di=m+1), packed-f32 epilogue, bias
// closed-form fold, fast/edge epilogue split, wT once/block via zero-VGPR
// global_load_lds, x via 9(5/4) float4 + in-reg transpose,
// launch_bounds(512,6), LDS 51.8KB.
// kh-pair: kh0:(hi1,oh1),(hi2,oh3); kh1:(hi0,oh0),(hi1,oh2);
//          kh2:(hi0,oh1),(hi1,oh3)   (validated R1-R15)

typedef __attribute__((ext_vector_type(8))) short bf16x8;
typedef __attribute__((ext_vector_type(4))) float f32x4;
typedef __attribute__((ext_vector_type(2))) float f32x2;

static __device__ __forceinline__ unsigned short f2bf(float f) {
    unsigned int u = __float_as_uint(f);
    u = (u + 0x7fffu + ((u >> 16) & 1u)) >> 16;   // RNE
    return (unsigned short)u;
}
static __device__ __forceinline__ unsigned cvtpk(float a, float b) {
    unsigned r;
    asm("v_cvt_pk_bf16_f32 %0, %1, %2" : "=v"(r) : "v"(a), "v"(b));
    return r;
}
static __device__ __forceinline__ void pkadd(f32x2& acc, f32x2 a) {
    asm("v_pk_add_f32 %0, %1, %0" : "+v"(acc) : "v"(a));
}
static __device__ __forceinline__ void pkfma(f32x2& acc, f32x2 a) {
    asm("v_pk_fma_f32 %0, %1, %1, %0" : "+v"(acc) : "v"(a));
}

// ---- w convert: w[ci][co][tap] fp32 -> wT[tap][co][slot] bf16, with
// bank-deconflict swizzle: slot s = (ci>>3) ^ ((co>>1)&3), elem e = ci&7.
__global__ __launch_bounds__(256)
void kw(const float* __restrict__ w, unsigned short* __restrict__ wT)
{
    const int idx = blockIdx.x * 256 + threadIdx.x;
    if (idx < 13824) {
        const int ci = idx & 31, co = (idx >> 5) & 15, tap = idx >> 9;
        const int s  = (ci >> 3) ^ ((co >> 1) & 3);
        const int dst = tap*512 + co*32 + s*8 + (ci & 7);
        wT[dst] = f2bf(w[(ci * 16 + co) * 27 + tap]);
    }
}

// ---- fused stage + convT + BN-stats + pool partials, 512 threads
__global__ __launch_bounds__(512, 6)
void convf2(const float* __restrict__ x,
            const unsigned short* __restrict__ wT,
            const float* __restrict__ bias,
            float* __restrict__ pooled,
            float* __restrict__ psum, float* __restrict__ psq)
{
    const int ht = blockIdx.x, dt = blockIdx.y, n = blockIdx.z;
    const int tid = threadIdx.x;
    const int vv = tid >> 6, lane = tid & 63;   // wave 0..7
    const int tw = vv & 1, odq = vv >> 1;       // ow half / od index
    const int c = lane & 15, qd = lane >> 4;    // co / K-granule

    __shared__ alignas(16) unsigned short xs[9504];    // 19008 B
    __shared__ alignas(16) unsigned short wTs[13824];  // 27648 B
    __shared__ float sred[8][16], qred[8][16], pbuf[4][2][8][16];

    const float bv = bias[c];                   // one 4B load, L1-resident

    // ---- stage wT -> LDS, zero VGPR (27 x 1KB chunks over 8 waves).
    // Linear copy -> the kw-side swizzle is inherited by wTs.
    #pragma unroll
    for (int i = 0; i < 4; ++i) {
        const int chunk = vv + 8 * i;           // wave-uniform
        if (chunk < 27) {
            __builtin_amdgcn_global_load_lds(
                (const char*)wT + chunk * 1024 + lane * 16,
                (char*)wTs + chunk * 1024,
                16, 0, 0);
        }
    }

    // ---- stage x: half h = tid>>8 covers planes p = 2i+h (5 / 4 planes)
    const int h = tid >> 8, ltid = tid & 255;
    const int ciS = ltid >> 3, q = ltid & 7;
    const int oL = ciS & 7;
    const int g = ciS >> 3;
    const float* xbase = x + (size_t)(n*32 + ciS)*32768 + 4*q;
    float4 F[5];
    #pragma unroll
    for (int i = 0; i < 5; ++i) {
        const int p = 2*i + h;
        if (p < 9) {
            const int di = p / 3, hp = p - 3*(p/3);
            const int id = 2*dt + di, ih = 2*ht + hp;
            F[i] = (id < 32 && ih < 32)
                 ? *(const float4*)(xbase + id*1024 + ih*32)
                 : make_float4(0.f, 0.f, 0.f, 0.f);
        }
    }
    const unsigned selP = (lane & 8) ? 0x07060302u : 0x01000504u;
    const int iwT = 4*q + (oL & 3), hT = oL >> 2;
    #pragma unroll
    for (int i = 0; i < 5; ++i) {
        const int p = 2*i + h;
        if (p < 9) {
            unsigned u0 = cvtpk(F[i].x, F[i].y);
            unsigned u1 = cvtpk(F[i].z, F[i].w);
            const unsigned a0 = (unsigned)__shfl_xor((int)u0, 8, 64);
            const unsigned a1 = (unsigned)__shfl_xor((int)u1, 8, 64);
            u0 = __builtin_amdgcn_perm(u0, a0, selP);
            u1 = __builtin_amdgcn_perm(u1, a1, selP);
            const unsigned s0 = (unsigned)__shfl_xor((int)u0, 16, 64);
            const unsigned s1 = (unsigned)__shfl_xor((int)u1, 16, 64);
            const unsigned w0 = (lane & 16) ? s1 : u0;
            const unsigned w1 = (lane & 16) ? u1 : s0;
            *(uint2*)(xs + p*1056 + g*264 + iwT*8 + 4*hT) = make_uint2(w0, w1);
        }
    }
    if (tid < 36) {
        const int dihi = tid >> 2, gg = tid & 3;
        *(uint4*)(xs + dihi*1056 + gg*264 + 256) = make_uint4(0,0,0,0);
    }

    __syncthreads();   // drains vmcnt -> wTs + xs ready

    // ---- compute: wave owns od = odq
    f32x4 acc[4][2];   // [oh][par]
    #pragma unroll
    for (int oh = 0; oh < 4; ++oh)
        #pragma unroll
        for (int par = 0; par < 2; ++par)
            acc[oh][par] = (f32x4){0.f,0.f,0.f,0.f};

    const int iwb = 16 * tw + c;
    // thread-invariant LDS bases; per-access offsets compile-time ->
    // ds_read_b128 with offset:imm, zero per-call VALU.
    // Bbase absorbs the bank-deconflict swizzle (qd ^ (c>>1)&3).
    const unsigned short* Abase = xs + qd*264 + iwb*8;
    const unsigned short* Bbase = wTs + c*32 + (qd ^ ((c >> 1) & 3))*8;

    constexpr int KHP[3][2][2] = {
        {{1,1},{2,3}},   // kh0
        {{0,0},{1,2}},   // kh1
        {{0,1},{1,3}},   // kh2
    };
    auto PH = [&](int tapbase, int di) {
        const unsigned short* Ab = Abase + di * 3168;   // one mul per PH
        #pragma unroll
        for (int kh = 0; kh < 3; ++kh) {
            const bf16x8 B0 = *(const bf16x8*)(Bbase + (tapbase + kh*3 + 0)*512);
            const bf16x8 B1 = *(const bf16x8*)(Bbase + (tapbase + kh*3 + 1)*512);
            const bf16x8 B2 = *(const bf16x8*)(Bbase + (tapbase + kh*3 + 2)*512);
            #pragma unroll
            for (int pp = 0; pp < 2; ++pp) {
                const int hi = KHP[kh][pp][0], oh = KHP[kh][pp][1];
                const bf16x8 A0 = *(const bf16x8*)(Ab + hi*1056);
                const bf16x8 A1 = *(const bf16x8*)(Ab + hi*1056 + 8);
                acc[oh][0] = __builtin_amdgcn_mfma_f32_16x16x32_bf16(
                    A0, B1, acc[oh][0], 0, 0, 0);
                acc[oh][1] = __builtin_amdgcn_mfma_f32_16x16x32_bf16(
                    A1, B0, acc[oh][1], 0, 0, 0);
                acc[oh][1] = __builtin_amdgcn_mfma_f32_16x16x32_bf16(
                    A0, B2, acc[oh][1], 0, 0, 0);
            }
        }
    };
    const int m = odq >> 1;
    if ((odq & 1) == 0) {
        PH(9, m);                 // even od=2m: kd=1, di=m
    } else {
        PH(18, m);                // odd od=2m+1: kd=2, di=m
        PH(0,  m + 1);            //              kd=0, di=m+1
    }

    // ---- epilogue on RAW acc (packed-f32 fast path)
    const bool inter = (dt < 15) && (ht < 15);
    const bool owx = (tw == 1) && (qd == 3);    // this thread holds ow==63
    float s_raw, sq_raw, cnt;
    float P0 = 0.f, P1 = 0.f;
    if (inter) {
        f32x2 Pa = (f32x2){0.f,0.f}, Pb = (f32x2){0.f,0.f};
        f32x2 Qa = (f32x2){0.f,0.f}, Qb = (f32x2){0.f,0.f};
        #pragma unroll
        for (int oh = 0; oh < 4; ++oh)
            #pragma unroll
            for (int par = 0; par < 2; ++par) {
                const f32x4 a = acc[oh][par];
                const f32x2 lo = (f32x2){a[0], a[1]};
                const f32x2 hi = (f32x2){a[2], a[3]};
                pkadd(Pa, lo); pkfma(Qa, lo);
                pkadd(Pb, hi); pkfma(Qb, hi);
            }
        P0 = Pa[0] + Pa[1];
        P1 = Pb[0] + Pb[1];
        float sqr = (Qa[0] + Qa[1]) + (Qb[0] + Qb[1]);
        float corr = 0.f, corrq = 0.f;
        if (owx) {                               // remove ow==63 (par1,r3)
            #pragma unroll
            for (int oh = 0; oh < 4; ++oh) {
                const float a = acc[oh][1][3];
                corr += a; corrq = fmaf(a, a, corrq);
            }
        }
        s_raw  = (P0 + P1) - corr;
        sq_raw = sqr - corrq;
        cnt    = owx ? 28.f : 32.f;
    } else {
        s_raw = 0.f; sq_raw = 0.f; cnt = 0.f;
        const bool odok = !(dt == 15 && odq == 3);
        #pragma unroll
        for (int oh = 0; oh < 4; ++oh) {
            const bool ohok = !(ht == 15 && oh == 3);
            #pragma unroll
            for (int par = 0; par < 2; ++par)
                #pragma unroll
                for (int r = 0; r < 4; ++r) {
                    const float a = acc[oh][par][r];
                    const bool owok = !(par == 1 && owx && r == 3);
                    const float mk = (odok && ohok && owok) ? 1.f : 0.f;
                    const float t = mk * a;
                    s_raw += t; sq_raw = fmaf(t, a, sq_raw); cnt += mk;
                    P0 += (r < 2) ? t : 0.f;
                    P1 += (r >= 2) ? t : 0.f;
                }
        }
        // edge blocks don't write pooled (inter==false), P values unused
    }
    // biased sums via closed form
    float s_b  = fmaf(cnt, bv, s_raw);
    float sq_b = fmaf(fmaf(cnt, bv, 2.f * s_raw), bv, sq_raw);

    s_b  += __shfl_xor(s_b, 16, 64);  s_b  += __shfl_xor(s_b, 32, 64);
    sq_b += __shfl_xor(sq_b, 16, 64); sq_b += __shfl_xor(sq_b, 32, 64);
    if (lane < 16) { sred[vv][lane] = s_b; qred[vv][lane] = sq_b; }
    pbuf[odq][tw][2*qd + 0][c] = P0;
    pbuf[odq][tw][2*qd + 1][c] = P1;

    __syncthreads();

    if (tid < 16) {
        const int blk = (n*16 + dt)*16 + ht;
        float S = 0.f, Q = 0.f;
        #pragma unroll
        for (int wv = 0; wv < 8; ++wv) { S += sred[wv][tid]; Q += qred[wv][tid]; }
        psum[tid*4096 + blk] = S;
        psq [tid*4096 + blk] = Q;
    }
    if (odq == 3 && inter) {                     // pool: sum 4 od partials (RAW)
        #pragma unroll
        for (int jj = 0; jj < 2; ++jj) {
            const int jl = 2*qd + jj, jg = 8*tw + jl;
            if (jg < 15) {
                const float tot = pbuf[0][tw][jl][c] + pbuf[1][tw][jl][c]
                                + pbuf[2][tw][jl][c] + pbuf[3][tw][jl][c];
                pooled[(n*16 + c)*3375 + dt*225 + ht*15 + jg] = tot * (1.f/64.f);
            }
        }
    }
}

__global__ void bnfinal(const float* __restrict__ psum, const float* __restrict__ psq,
                        const float* __restrict__ gamma, const float* __restrict__ beta,
                        const float* __restrict__ bias,
                        float* __restrict__ bn)
{
    const int co = blockIdx.x;
    const int t  = threadIdx.x;
    float S = 0, Q = 0;
    for (int blk = t; blk < 4096; blk += 256) {
        S += psum[co*4096 + blk];
        Q += psq [co*4096 + blk];
    }
    #pragma unroll
    for (int off = 32; off > 0; off >>= 1) {
        S += __shfl_down(S, off, 64);
        Q += __shfl_down(Q, off, 64);
    }
    __shared__ float rs[4], rq[4];
    if ((t & 63) == 0) { rs[t >> 6] = S; rq[t >> 6] = Q; }
    __syncthreads();
    if (t == 0) {
        S = rs[0] + rs[1] + rs[2] + rs[3];
        Q = rq[0] + rq[1] + rq[2] + rq[3];
        const float cnt = 16.f * 63.f * 63.f * 63.f;
        const float mean = S / cnt;
        const float var  = Q / cnt - mean * mean;
        const float inv  = rsqrtf(var + 1e-5f);
        const float sc   = inv * gamma[co];
        bn[co]      = sc;
        // pooled stores RAW conv mean; bias enters the affine offset
        bn[16 + co] = beta[co] + (bias[co] - mean) * sc;
    }
}

__global__ void finalize(const float* __restrict__ pooled, const float* __restrict__ bn,
                         float* __restrict__ out)
{
    const int i  = blockIdx.x * 256 + threadIdx.x;   // 864000 = 3375*256
    const int co = (i / 3375) & 15;
    out[i] = pooled[i] * bn[co] + bn[16 + co];
}

extern "C" void kernel_launch(void* const* d_in, const int* in_sizes, int n_in,
                              void* d_out, int out_size, void* d_ws, size_t ws_size,
                              hipStream_t stream)
{
    const float* x     = (const float*)d_in[0];
    const float* w     = (const float*)d_in[1];
    const float* b     = (const float*)d_in[2];
    const float* gamma = (const float*)d_in[3];
    const float* beta  = (const float*)d_in[4];
    float* out = (float*)d_out;

    char* wsb = (char*)d_ws;
    unsigned short* wT = (unsigned short*)wsb;        // 27,648 B
    float* pooled = (float*)(wsb + 27648);            // 3,456,000 B
    float* psum   = (float*)(wsb + 27648 + 3456000);  // 262,144 B
    float* psq    = (float*)(wsb + 27648 + 3456000 + 262144);
    float* bn     = (float*)(wsb + 27648 + 3456000 + 2*262144);

    kw<<<54, 256, 0, stream>>>(w, wT);
    dim3 grid(16, 16, 16);   // (ht, dt, n)
    convf2<<<grid, 512, 0, stream>>>(x, wT, b, pooled, psum, psq);
    bnfinal<<<16, 256, 0, stream>>>(psum, psq, gamma, beta, b, bn);
    finalize<<<3375, 256, 0, stream>>>(pooled, bn, out);
}

// Round 12
// 128.675 us; speedup vs baseline: 1.0191x; 1.0139x over previous
//
#include <hip/hip_runtime.h>

// ConvT3d(32->16,k3,s2,p1)+BN+4^3 avgpool, bf16 MFMA.
// R17: DS-op cut. R16 post-mortem: bank-conflict fix didn't move wall ->
// floor is DS-op COUNT (252 hot b128/block + ~40 staging wave-ops ~= 23us
// LDS-pipe occupancy/CU, largest computed floor). Fix: cross-kh A-caching.
// KHP pairs share hi planes between consecutive kh; reorder kh 1->2->0:
//   kh1 loads A(hi0),A(hi1); kh2 reuses both; kh0 reuses A(hi1), loads
//   A(hi2). 12 -> 6 A-reads per PH (even wave 21->15, odd 42->30 DS ops,
//   -29% hot loop). A-cache = 2 plane-pairs = 16 VGPR transient; peak ~80
//   <= 85 cap at (512,6) -> occupancy preserved. Same 54 MFMA triples,
//   kh-permuted accumulation order only (bf16 noise floor).
// Frozen from R16: B-swizzle (kw slot s = (ci>>3)^((co>>1)&3), reader base
// qd^((c>>1)&3)), 512 thr, wave odq owns od (m=odq>>1; even: kd=1 di=m;
// odd: kd=2 di=m + kd=0 di=m+1), packed-f32 epilogue, bias closed-form,
// fast/edge split, wT once/block zero-VGPR global_load_lds, x 9(5/4)
// float4 + in-reg transpose, launch_bounds(512,6), LDS 51.8KB.
// MFMA triple (validated R1-R16): acc[oh][0]+=A0*B1; acc[oh][1]+=A1*B0;
//   acc[oh][1]+=A0*B2.
// kh-pair: kh0:(hi1,oh1),(hi2,oh3); kh1:(hi0,oh0),(hi1,oh2);
//          kh2:(hi0,oh1),(hi1,oh3)

typedef __attribute__((ext_vector_type(8))) short bf16x8;
typedef __attribute__((ext_vector_type(4))) float f32x4;
typedef __attribute__((ext_vector_type(2))) float f32x2;

static __device__ __forceinline__ unsigned short f2bf(float f) {
    unsigned int u = __float_as_uint(f);
    u = (u + 0x7fffu + ((u >> 16) & 1u)) >> 16;   // RNE
    return (unsigned short)u;
}
static __device__ __forceinline__ unsigned cvtpk(float a, float b) {
    unsigned r;
    asm("v_cvt_pk_bf16_f32 %0, %1, %2" : "=v"(r) : "v"(a), "v"(b));
    return r;
}
static __device__ __forceinline__ void pkadd(f32x2& acc, f32x2 a) {
    asm("v_pk_add_f32 %0, %1, %0" : "+v"(acc) : "v"(a));
}
static __device__ __forceinline__ void pkfma(f32x2& acc, f32x2 a) {
    asm("v_pk_fma_f32 %0, %1, %1, %0" : "+v"(acc) : "v"(a));
}

// ---- w convert: w[ci][co][tap] fp32 -> wT[tap][co][slot] bf16, with
// bank-deconflict swizzle: slot s = (ci>>3) ^ ((co>>1)&3), elem e = ci&7.
__global__ __launch_bounds__(256)
void kw(const float* __restrict__ w, unsigned short* __restrict__ wT)
{
    const int idx = blockIdx.x * 256 + threadIdx.x;
    if (idx < 13824) {
        const int ci = idx & 31, co = (idx >> 5) & 15, tap = idx >> 9;
        const int s  = (ci >> 3) ^ ((co >> 1) & 3);
        const int dst = tap*512 + co*32 + s*8 + (ci & 7);
        wT[dst] = f2bf(w[(ci * 16 + co) * 27 + tap]);
    }
}

// ---- fused stage + convT + BN-stats + pool partials, 512 threads
__global__ __launch_bounds__(512, 6)
void convf2(const float* __restrict__ x,
            const unsigned short* __restrict__ wT,
            const float* __restrict__ bias,
            float* __restrict__ pooled,
            float* __restrict__ psum, float* __restrict__ psq)
{
    const int ht = blockIdx.x, dt = blockIdx.y, n = blockIdx.z;
    const int tid = threadIdx.x;
    const int vv = tid >> 6, lane = tid & 63;   // wave 0..7
    const int tw = vv & 1, odq = vv >> 1;       // ow half / od index
    const int c = lane & 15, qd = lane >> 4;    // co / K-granule

    __shared__ alignas(16) unsigned short xs[9504];    // 19008 B
    __shared__ alignas(16) unsigned short wTs[13824];  // 27648 B
    __shared__ float sred[8][16], qred[8][16], pbuf[4][2][8][16];

    const float bv = bias[c];                   // one 4B load, L1-resident

    // ---- stage wT -> LDS, zero VGPR (27 x 1KB chunks over 8 waves).
    // Linear copy -> the kw-side swizzle is inherited by wTs.
    #pragma unroll
    for (int i = 0; i < 4; ++i) {
        const int chunk = vv + 8 * i;           // wave-uniform
        if (chunk < 27) {
            __builtin_amdgcn_global_load_lds(
                (const char*)wT + chunk * 1024 + lane * 16,
                (char*)wTs + chunk * 1024,
                16, 0, 0);
        }
    }

    // ---- stage x: half h = tid>>8 covers planes p = 2i+h (5 / 4 planes)
    const int h = tid >> 8, ltid = tid & 255;
    const int ciS = ltid >> 3, q = ltid & 7;
    const int oL = ciS & 7;
    const int g = ciS >> 3;
    const float* xbase = x + (size_t)(n*32 + ciS)*32768 + 4*q;
    float4 F[5];
    #pragma unroll
    for (int i = 0; i < 5; ++i) {
        const int p = 2*i + h;
        if (p < 9) {
            const int di = p / 3, hp = p - 3*(p/3);
            const int id = 2*dt + di, ih = 2*ht + hp;
            F[i] = (id < 32 && ih < 32)
                 ? *(const float4*)(xbase + id*1024 + ih*32)
                 : make_float4(0.f, 0.f, 0.f, 0.f);
        }
    }
    const unsigned selP = (lane & 8) ? 0x07060302u : 0x01000504u;
    const int iwT = 4*q + (oL & 3), hT = oL >> 2;
    #pragma unroll
    for (int i = 0; i < 5; ++i) {
        const int p = 2*i + h;
        if (p < 9) {
            unsigned u0 = cvtpk(F[i].x, F[i].y);
            unsigned u1 = cvtpk(F[i].z, F[i].w);
            const unsigned a0 = (unsigned)__shfl_xor((int)u0, 8, 64);
            const unsigned a1 = (unsigned)__shfl_xor((int)u1, 8, 64);
            u0 = __builtin_amdgcn_perm(u0, a0, selP);
            u1 = __builtin_amdgcn_perm(u1, a1, selP);
            const unsigned s0 = (unsigned)__shfl_xor((int)u0, 16, 64);
            const unsigned s1 = (unsigned)__shfl_xor((int)u1, 16, 64);
            const unsigned w0 = (lane & 16) ? s1 : u0;
            const unsigned w1 = (lane & 16) ? u1 : s0;
            *(uint2*)(xs + p*1056 + g*264 + iwT*8 + 4*hT) = make_uint2(w0, w1);
        }
    }
    if (tid < 36) {
        const int dihi = tid >> 2, gg = tid & 3;
        *(uint4*)(xs + dihi*1056 + gg*264 + 256) = make_uint4(0,0,0,0);
    }

    __syncthreads();   // drains vmcnt -> wTs + xs ready

    // ---- compute: wave owns od = odq
    f32x4 acc[4][2];   // [oh][par]
    #pragma unroll
    for (int oh = 0; oh < 4; ++oh)
        #pragma unroll
        for (int par = 0; par < 2; ++par)
            acc[oh][par] = (f32x4){0.f,0.f,0.f,0.f};

    const int iwb = 16 * tw + c;
    // thread-invariant LDS bases; per-access offsets compile-time ->
    // ds_read_b128 with offset:imm. Bbase absorbs the R16 bank swizzle.
    const unsigned short* Abase = xs + qd*264 + iwb*8;
    const unsigned short* Bbase = wTs + c*32 + (qd ^ ((c >> 1) & 3))*8;

    // MFMA triple on one (A-pair, B-triple): validated R1-R16 pattern
    auto TRI = [&](int oh, const bf16x8& A0, const bf16x8& A1,
                   const bf16x8& B0, const bf16x8& B1, const bf16x8& B2) {
        acc[oh][0] = __builtin_amdgcn_mfma_f32_16x16x32_bf16(A0, B1, acc[oh][0], 0, 0, 0);
        acc[oh][1] = __builtin_amdgcn_mfma_f32_16x16x32_bf16(A1, B0, acc[oh][1], 0, 0, 0);
        acc[oh][1] = __builtin_amdgcn_mfma_f32_16x16x32_bf16(A0, B2, acc[oh][1], 0, 0, 0);
    };
    // PH with cross-kh A-cache, kh order 1 -> 2 -> 0:
    //   kh1: (hi0,oh0),(hi1,oh2)   loads A(hi0), A(hi1)
    //   kh2: (hi0,oh1),(hi1,oh3)   reuses both
    //   kh0: (hi1,oh1),(hi2,oh3)   reuses A(hi1), loads A(hi2)
    auto PH = [&](int tapbase, int di) {
        const unsigned short* Ab = Abase + di * 3168;   // one mul per PH
        bf16x8 Aa0 = *(const bf16x8*)(Ab + 0);          // hi0
        bf16x8 Aa1 = *(const bf16x8*)(Ab + 8);
        bf16x8 Ab0 = *(const bf16x8*)(Ab + 1056);       // hi1
        bf16x8 Ab1 = *(const bf16x8*)(Ab + 1056 + 8);
        {   // kh1
            const bf16x8 B0 = *(const bf16x8*)(Bbase + (tapbase + 3)*512);
            const bf16x8 B1 = *(const bf16x8*)(Bbase + (tapbase + 4)*512);
            const bf16x8 B2 = *(const bf16x8*)(Bbase + (tapbase + 5)*512);
            TRI(0, Aa0, Aa1, B0, B1, B2);
            TRI(2, Ab0, Ab1, B0, B1, B2);
        }
        {   // kh2
            const bf16x8 B0 = *(const bf16x8*)(Bbase + (tapbase + 6)*512);
            const bf16x8 B1 = *(const bf16x8*)(Bbase + (tapbase + 7)*512);
            const bf16x8 B2 = *(const bf16x8*)(Bbase + (tapbase + 8)*512);
            TRI(1, Aa0, Aa1, B0, B1, B2);
            TRI(3, Ab0, Ab1, B0, B1, B2);
        }
        {   // kh0: reuse hi1 (Ab*), load hi2 into Aa*
            Aa0 = *(const bf16x8*)(Ab + 2112);          // hi2
            Aa1 = *(const bf16x8*)(Ab + 2112 + 8);
            const bf16x8 B0 = *(const bf16x8*)(Bbase + (tapbase + 0)*512);
            const bf16x8 B1 = *(const bf16x8*)(Bbase + (tapbase + 1)*512);
            const bf16x8 B2 = *(const bf16x8*)(Bbase + (tapbase + 2)*512);
            TRI(1, Ab0, Ab1, B0, B1, B2);
            TRI(3, Aa0, Aa1, B0, B1, B2);
        }
    };
    const int m = odq >> 1;
    if ((odq & 1) == 0) {
        PH(9, m);                 // even od=2m: kd=1, di=m
    } else {
        PH(18, m);                // odd od=2m+1: kd=2, di=m
        PH(0,  m + 1);            //              kd=0, di=m+1
    }

    // ---- epilogue on RAW acc (packed-f32 fast path)
    const bool inter = (dt < 15) && (ht < 15);
    const bool owx = (tw == 1) && (qd == 3);    // this thread holds ow==63
    float s_raw, sq_raw, cnt;
    float P0 = 0.f, P1 = 0.f;
    if (inter) {
        f32x2 Pa = (f32x2){0.f,0.f}, Pb = (f32x2){0.f,0.f};
        f32x2 Qa = (f32x2){0.f,0.f}, Qb = (f32x2){0.f,0.f};
        #pragma unroll
        for (int oh = 0; oh < 4; ++oh)
            #pragma unroll
            for (int par = 0; par < 2; ++par) {
                const f32x4 a = acc[oh][par];
                const f32x2 lo = (f32x2){a[0], a[1]};
                const f32x2 hi = (f32x2){a[2], a[3]};
                pkadd(Pa, lo); pkfma(Qa, lo);
                pkadd(Pb, hi); pkfma(Qb, hi);
            }
        P0 = Pa[0] + Pa[1];
        P1 = Pb[0] + Pb[1];
        float sqr = (Qa[0] + Qa[1]) + (Qb[0] + Qb[1]);
        float corr = 0.f, corrq = 0.f;
        if (owx) {                               // remove ow==63 (par1,r3)
            #pragma unroll
            for (int oh = 0; oh < 4; ++oh) {
                const float a = acc[oh][1][3];
                corr += a; corrq = fmaf(a, a, corrq);
            }
        }
        s_raw  = (P0 + P1) - corr;
        sq_raw = sqr - corrq;
        cnt    = owx ? 28.f : 32.f;
    } else {
        s_raw = 0.f; sq_raw = 0.f; cnt = 0.f;
        const bool odok = !(dt == 15 && odq == 3);
        #pragma unroll
        for (int oh = 0; oh < 4; ++oh) {
            const bool ohok = !(ht == 15 && oh == 3);
            #pragma unroll
            for (int par = 0; par < 2; ++par)
                #pragma unroll
                for (int r = 0; r < 4; ++r) {
                    const float a = acc[oh][par][r];
                    const bool owok = !(par == 1 && owx && r == 3);
                    const float mk = (odok && ohok && owok) ? 1.f : 0.f;
                    const float t = mk * a;
                    s_raw += t; sq_raw = fmaf(t, a, sq_raw); cnt += mk;
                    P0 += (r < 2) ? t : 0.f;
                    P1 += (r >= 2) ? t : 0.f;
                }
        }
        // edge blocks don't write pooled (inter==false), P values unused
    }
    // biased sums via closed form
    float s_b  = fmaf(cnt, bv, s_raw);
    float sq_b = fmaf(fmaf(cnt, bv, 2.f * s_raw), bv, sq_raw);

    s_b  += __shfl_xor(s_b, 16, 64);  s_b  += __shfl_xor(s_b, 32, 64);
    sq_b += __shfl_xor(sq_b, 16, 64); sq_b += __shfl_xor(sq_b, 32, 64);
    if (lane < 16) { sred[vv][lane] = s_b; qred[vv][lane] = sq_b; }
    pbuf[odq][tw][2*qd + 0][c] = P0;
    pbuf[odq][tw][2*qd + 1][c] = P1;

    __syncthreads();

    if (tid < 16) {
        const int blk = (n*16 + dt)*16 + ht;
        float S = 0.f, Q = 0.f;
        #pragma unroll
        for (int wv = 0; wv < 8; ++wv) { S += sred[wv][tid]; Q += qred[wv][tid]; }
        psum[tid*4096 + blk] = S;
        psq [tid*4096 + blk] = Q;
    }
    if (odq == 3 && inter) {                     // pool: sum 4 od partials (RAW)
        #pragma unroll
        for (int jj = 0; jj < 2; ++jj) {
            const int jl = 2*qd + jj, jg = 8*tw + jl;
            if (jg < 15) {
                const float tot = pbuf[0][tw][jl][c] + pbuf[1][tw][jl][c]
                                + pbuf[2][tw][jl][c] + pbuf[3][tw][jl][c];
                pooled[(n*16 + c)*3375 + dt*225 + ht*15 + jg] = tot * (1.f/64.f);
            }
        }
    }
}

__global__ void bnfinal(const float* __restrict__ psum, const float* __restrict__ psq,
                        const float* __restrict__ gamma, const float* __restrict__ beta,
                        const float* __restrict__ bias,
                        float* __restrict__ bn)
{
    const int co = blockIdx.x;
    const int t  = threadIdx.x;
    float S = 0, Q = 0;
    for (int blk = t; blk < 4096; blk += 256) {
        S += psum[co*4096 + blk];
        Q += psq [co*4096 + blk];
    }
    #pragma unroll
    for (int off = 32; off > 0; off >>= 1) {
        S += __shfl_down(S, off, 64);
        Q += __shfl_down(Q, off, 64);
    }
    __shared__ float rs[4], rq[4];
    if ((t & 63) == 0) { rs[t >> 6] = S; rq[t >> 6] = Q; }
    __syncthreads();
    if (t == 0) {
        S = rs[0] + rs[1] + rs[2] + rs[3];
        Q = rq[0] + rq[1] + rq[2] + rq[3];
        const float cnt = 16.f * 63.f * 63.f * 63.f;
        const float mean = S / cnt;
        const float var  = Q / cnt - mean * mean;
        const float inv  = rsqrtf(var + 1e-5f);
        const float sc   = inv * gamma[co];
        bn[co]      = sc;
        // pooled stores RAW conv mean; bias enters the affine offset
        bn[16 + co] = beta[co] + (bias[co] - mean) * sc;
    }
}

__global__ void finalize(const float* __restrict__ pooled, const float* __restrict__ bn,
                         float* __restrict__ out)
{
    const int i  = blockIdx.x * 256 + threadIdx.x;   // 864000 = 3375*256
    const int co = (i / 3375) & 15;
    out[i] = pooled[i] * bn[co] + bn[16 + co];
}

extern "C" void kernel_launch(void* const* d_in, const int* in_sizes, int n_in,
                              void* d_out, int out_size, void* d_ws, size_t ws_size,
                              hipStream_t stream)
{
    const float* x     = (const float*)d_in[0];
    const float* w     = (const float*)d_in[1];
    const float* b     = (const float*)d_in[2];
    const float* gamma = (const float*)d_in[3];
    const float* beta  = (const float*)d_in[4];
    float* out = (float*)d_out;

    char* wsb = (char*)d_ws;
    unsigned short* wT = (unsigned short*)wsb;        // 27,648 B
    float* pooled = (float*)(wsb + 27648);            // 3,456,000 B
    float* psum   = (float*)(wsb + 27648 + 3456000);  // 262,144 B
    float* psq    = (float*)(wsb + 27648 + 3456000 + 262144);
    float* bn     = (float*)(wsb + 27648 + 3456000 + 2*262144);

    kw<<<54, 256, 0, stream>>>(w, wT);
    dim3 grid(16, 16, 16);   // (ht, dt, n)
    convf2<<<grid, 512, 0, stream>>>(x, wT, b, pooled, psum, psq);
    bnfinal<<<16, 256, 0, stream>>>(psum, psq, gamma, beta, b, bn);
    finalize<<<3375, 256, 0, stream>>>(pooled, bn, out);
}

// Round 13
// 122.633 us; speedup vs baseline: 1.0693x; 1.0493x over previous
//
#include <hip/hip_runtime.h>

// ConvT3d(32->16,k3,s2,p1)+BN+4^3 avgpool, bf16 MFMA.
// R18: persistent 8-tile blocks. Evidence (R10-R17): every pipe fix leaves
// convf2 at ~39-42us while NO pipe saturates (HBM 20%, VALU 36%, MFMA 12%,
// DS ~40%) -> the cost is phase serialization across 16 short block-
// generations/CU (memory idle during compute, ALUs idle during stage).
// Fix: grid (16,16,2) = 512 blocks = 2/CU persistent; each block runs 8
// n-tiles with double-buffered xs. Per tile: ISSUE(t+1) -> compute(t) ->
// partials -> bar -> pooled(t) || TRANSP(t+1) -> bar. x-load latency hides
// under compute every tile; wT staged ONCE per 8 tiles; BN sums accumulate
// in regs (bias closed-form applied once at end; cnt scales x8).
// LDS 2x19.0(xs) + 27.6(wTs) + 5.1 = 69.1KB -> 2 blocks/CU, 16 waves/CU
// steady. launch_bounds(512,4): peak ~105 regs (F20 + acc32 + Acache16 +
// B12 + misc) <= 128. psum blocks 4096 -> 512 (bnfinal loop updated).
// Kept: R16 B-swizzle (kw slot s=(ci>>3)^((co>>1)&3), reader base
// qd^((c>>1)&3)); R17 cross-kh A-cache (kh order 1->2->0, 6 A-reads/PH);
// 512-thr wave-odq decomposition (m=odq>>1; even od: kd=1 di=m; odd:
// kd=2 di=m + kd=0 di=m+1); packed-f32 epilogue; fast/edge split;
// zero-VGPR global_load_lds wT; x 9(5/4) float4 + in-reg transpose.
// MFMA triple (validated R1-R17): acc[oh][0]+=A0*B1; acc[oh][1]+=A1*B0;
//   acc[oh][1]+=A0*B2.
// kh-pair: kh0:(hi1,oh1),(hi2,oh3); kh1:(hi0,oh0),(hi1,oh2);
//          kh2:(hi0,oh1),(hi1,oh3)

typedef __attribute__((ext_vector_type(8))) short bf16x8;
typedef __attribute__((ext_vector_type(4))) float f32x4;
typedef __attribute__((ext_vector_type(2))) float f32x2;

static __device__ __forceinline__ unsigned short f2bf(float f) {
    unsigned int u = __float_as_uint(f);
    u = (u + 0x7fffu + ((u >> 16) & 1u)) >> 16;   // RNE
    return (unsigned short)u;
}
static __device__ __forceinline__ unsigned cvtpk(float a, float b) {
    unsigned r;
    asm("v_cvt_pk_bf16_f32 %0, %1, %2" : "=v"(r) : "v"(a), "v"(b));
    return r;
}
static __device__ __forceinline__ void pkadd(f32x2& acc, f32x2 a) {
    asm("v_pk_add_f32 %0, %1, %0" : "+v"(acc) : "v"(a));
}
static __device__ __forceinline__ void pkfma(f32x2& acc, f32x2 a) {
    asm("v_pk_fma_f32 %0, %1, %1, %0" : "+v"(acc) : "v"(a));
}

// ---- w convert: w[ci][co][tap] fp32 -> wT[tap][co][slot] bf16, with
// bank-deconflict swizzle: slot s = (ci>>3) ^ ((co>>1)&3), elem e = ci&7.
__global__ __launch_bounds__(256)
void kw(const float* __restrict__ w, unsigned short* __restrict__ wT)
{
    const int idx = blockIdx.x * 256 + threadIdx.x;
    if (idx < 13824) {
        const int ci = idx & 31, co = (idx >> 5) & 15, tap = idx >> 9;
        const int s  = (ci >> 3) ^ ((co >> 1) & 3);
        const int dst = tap*512 + co*32 + s*8 + (ci & 7);
        wT[dst] = f2bf(w[(ci * 16 + co) * 27 + tap]);
    }
}

// ---- fused stage + convT + BN-stats + pool partials, 8 n-tiles/block
__global__ __launch_bounds__(512, 4)
void convf2(const float* __restrict__ x,
            const unsigned short* __restrict__ wT,
            const float* __restrict__ bias,
            float* __restrict__ pooled,
            float* __restrict__ psum, float* __restrict__ psq)
{
    const int ht = blockIdx.x, dt = blockIdx.y, bz = blockIdx.z;
    const int n0 = bz * 8;
    const int tid = threadIdx.x;
    const int vv = tid >> 6, lane = tid & 63;   // wave 0..7
    const int tw = vv & 1, odq = vv >> 1;       // ow half / od index
    const int c = lane & 15, qd = lane >> 4;    // co / K-granule

    __shared__ alignas(16) unsigned short xs[2][9504];   // 2 x 19008 B
    __shared__ alignas(16) unsigned short wTs[13824];    // 27648 B
    __shared__ float sred[8][16], qred[8][16], pbuf[4][2][8][16];

    const float bv = bias[c];

    // ---- stage wT -> LDS once per block, zero VGPR (27 x 1KB chunks)
    #pragma unroll
    for (int i = 0; i < 4; ++i) {
        const int chunk = vv + 8 * i;           // wave-uniform
        if (chunk < 27) {
            __builtin_amdgcn_global_load_lds(
                (const char*)wT + chunk * 1024 + lane * 16,
                (char*)wTs + chunk * 1024,
                16, 0, 0);
        }
    }

    // ---- x staging geometry (block-uniform plane offsets/masks)
    const int h = tid >> 8, ltid = tid & 255;
    const int ciS = ltid >> 3, q = ltid & 7;
    const int oL = ciS & 7;
    const int g = ciS >> 3;
    int offp[5]; bool okp[5];
    #pragma unroll
    for (int i = 0; i < 5; ++i) {
        const int p = 2*i + h;
        const int di = p / 3, hp = p - 3*(p/3);
        const int id = 2*dt + di, ih = 2*ht + hp;
        okp[i]  = (p < 9) && (id < 32) && (ih < 32);
        offp[i] = id*1024 + ih*32;
    }
    const float* xci = x + (size_t)ciS*32768 + 4*q;
    float4 F[5];
    auto ISSUE = [&](int nn) {
        const float* xb = xci + (size_t)nn*32*32768;
        #pragma unroll
        for (int i = 0; i < 5; ++i)
            F[i] = okp[i] ? *(const float4*)(xb + offp[i])
                          : make_float4(0.f, 0.f, 0.f, 0.f);
    };
    const unsigned selP = (lane & 8) ? 0x07060302u : 0x01000504u;
    const int iwT = 4*q + (oL & 3), hT = oL >> 2;
    auto TRANSP = [&](unsigned short* xp) {
        #pragma unroll
        for (int i = 0; i < 5; ++i) {
            const int p = 2*i + h;
            if (p < 9) {
                unsigned u0 = cvtpk(F[i].x, F[i].y);
                unsigned u1 = cvtpk(F[i].z, F[i].w);
                const unsigned a0 = (unsigned)__shfl_xor((int)u0, 8, 64);
                const unsigned a1 = (unsigned)__shfl_xor((int)u1, 8, 64);
                u0 = __builtin_amdgcn_perm(u0, a0, selP);
                u1 = __builtin_amdgcn_perm(u1, a1, selP);
                const unsigned s0 = (unsigned)__shfl_xor((int)u0, 16, 64);
                const unsigned s1 = (unsigned)__shfl_xor((int)u1, 16, 64);
                const unsigned w0 = (lane & 16) ? s1 : u0;
                const unsigned w1 = (lane & 16) ? u1 : s0;
                *(uint2*)(xp + p*1056 + g*264 + iwT*8 + 4*hT) = make_uint2(w0, w1);
            }
        }
    };

    // prologue: tile 0 staging + static zero columns (iw=32, both buffers)
    ISSUE(n0);
    if (tid < 36) {
        const int dihi = tid >> 2, gg = tid & 3;
        *(uint4*)(&xs[0][0] + dihi*1056 + gg*264 + 256) = make_uint4(0,0,0,0);
        *(uint4*)(&xs[1][0] + dihi*1056 + gg*264 + 256) = make_uint4(0,0,0,0);
    }
    TRANSP(&xs[0][0]);
    __syncthreads();   // drains vmcnt -> wTs + xs[0] ready

    const int iwb = 16 * tw + c;
    const unsigned short* Bbase = wTs + c*32 + (qd ^ ((c >> 1) & 3))*8;
    const bool inter = (dt < 15) && (ht < 15);
    const bool owx = (tw == 1) && (qd == 3);
    const int m = odq >> 1;

    float s_rawA = 0.f, sq_rawA = 0.f;          // across 8 tiles

    for (int tt = 0; tt < 8; ++tt) {
        const int cur = tt & 1;
        if (tt < 7) ISSUE(n0 + tt + 1);          // prefetch next tile's x

        f32x4 acc[4][2];   // [oh][par]
        #pragma unroll
        for (int oh = 0; oh < 4; ++oh)
            #pragma unroll
            for (int par = 0; par < 2; ++par)
                acc[oh][par] = (f32x4){0.f,0.f,0.f,0.f};

        const unsigned short* Abase = &xs[cur][0] + qd*264 + iwb*8;

        auto TRI = [&](int oh, const bf16x8& A0, const bf16x8& A1,
                       const bf16x8& B0, const bf16x8& B1, const bf16x8& B2) {
            acc[oh][0] = __builtin_amdgcn_mfma_f32_16x16x32_bf16(A0, B1, acc[oh][0], 0, 0, 0);
            acc[oh][1] = __builtin_amdgcn_mfma_f32_16x16x32_bf16(A1, B0, acc[oh][1], 0, 0, 0);
            acc[oh][1] = __builtin_amdgcn_mfma_f32_16x16x32_bf16(A0, B2, acc[oh][1], 0, 0, 0);
        };
        // PH with cross-kh A-cache, kh order 1 -> 2 -> 0 (R17)
        auto PH = [&](int tapbase, int di) {
            const unsigned short* Ab = Abase + di * 3168;
            bf16x8 Aa0 = *(const bf16x8*)(Ab + 0);          // hi0
            bf16x8 Aa1 = *(const bf16x8*)(Ab + 8);
            bf16x8 Ab0 = *(const bf16x8*)(Ab + 1056);       // hi1
            bf16x8 Ab1 = *(const bf16x8*)(Ab + 1056 + 8);
            {   // kh1
                const bf16x8 B0 = *(const bf16x8*)(Bbase + (tapbase + 3)*512);
                const bf16x8 B1 = *(const bf16x8*)(Bbase + (tapbase + 4)*512);
                const bf16x8 B2 = *(const bf16x8*)(Bbase + (tapbase + 5)*512);
                TRI(0, Aa0, Aa1, B0, B1, B2);
                TRI(2, Ab0, Ab1, B0, B1, B2);
            }
            {   // kh2
                const bf16x8 B0 = *(const bf16x8*)(Bbase + (tapbase + 6)*512);
                const bf16x8 B1 = *(const bf16x8*)(Bbase + (tapbase + 7)*512);
                const bf16x8 B2 = *(const bf16x8*)(Bbase + (tapbase + 8)*512);
                TRI(1, Aa0, Aa1, B0, B1, B2);
                TRI(3, Ab0, Ab1, B0, B1, B2);
            }
            {   // kh0: reuse hi1 (Ab*), load hi2 into Aa*
                Aa0 = *(const bf16x8*)(Ab + 2112);          // hi2
                Aa1 = *(const bf16x8*)(Ab + 2112 + 8);
                const bf16x8 B0 = *(const bf16x8*)(Bbase + (tapbase + 0)*512);
                const bf16x8 B1 = *(const bf16x8*)(Bbase + (tapbase + 1)*512);
                const bf16x8 B2 = *(const bf16x8*)(Bbase + (tapbase + 2)*512);
                TRI(1, Ab0, Ab1, B0, B1, B2);
                TRI(3, Aa0, Aa1, B0, B1, B2);
            }
        };
        if ((odq & 1) == 0) {
            PH(9, m);                 // even od=2m: kd=1, di=m
        } else {
            PH(18, m);                // odd od=2m+1: kd=2, di=m
            PH(0,  m + 1);            //              kd=0, di=m+1
        }

        // ---- epilogue partials on RAW acc (packed-f32 fast path)
        float s_raw, sq_raw;
        float P0 = 0.f, P1 = 0.f;
        if (inter) {
            f32x2 Pa = (f32x2){0.f,0.f}, Pb = (f32x2){0.f,0.f};
            f32x2 Qa = (f32x2){0.f,0.f}, Qb = (f32x2){0.f,0.f};
            #pragma unroll
            for (int oh = 0; oh < 4; ++oh)
                #pragma unroll
                for (int par = 0; par < 2; ++par) {
                    const f32x4 a = acc[oh][par];
                    const f32x2 lo = (f32x2){a[0], a[1]};
                    const f32x2 hi = (f32x2){a[2], a[3]};
                    pkadd(Pa, lo); pkfma(Qa, lo);
                    pkadd(Pb, hi); pkfma(Qb, hi);
                }
            P0 = Pa[0] + Pa[1];
            P1 = Pb[0] + Pb[1];
            float sqr = (Qa[0] + Qa[1]) + (Qb[0] + Qb[1]);
            float corr = 0.f, corrq = 0.f;
            if (owx) {                               // remove ow==63 (par1,r3)
                #pragma unroll
                for (int oh = 0; oh < 4; ++oh) {
                    const float a = acc[oh][1][3];
                    corr += a; corrq = fmaf(a, a, corrq);
                }
            }
            s_raw  = (P0 + P1) - corr;
            sq_raw = sqr - corrq;
        } else {
            s_raw = 0.f; sq_raw = 0.f;
            const bool odok = !(dt == 15 && odq == 3);
            #pragma unroll
            for (int oh = 0; oh < 4; ++oh) {
                const bool ohok = !(ht == 15 && oh == 3);
                #pragma unroll
                for (int par = 0; par < 2; ++par)
                    #pragma unroll
                    for (int r = 0; r < 4; ++r) {
                        const float a = acc[oh][par][r];
                        const bool owok = !(par == 1 && owx && r == 3);
                        const float mk = (odok && ohok && owok) ? 1.f : 0.f;
                        const float t = mk * a;
                        s_raw += t; sq_raw = fmaf(t, a, sq_raw);
                    }
            }
        }
        s_rawA += s_raw; sq_rawA += sq_raw;

        pbuf[odq][tw][2*qd + 0][c] = P0;
        pbuf[odq][tw][2*qd + 1][c] = P1;
        __syncthreads();                         // pbuf published, xs[cur] read done

        if (odq == 3 && inter) {                 // pool write (overlaps TRANSP)
            #pragma unroll
            for (int jj = 0; jj < 2; ++jj) {
                const int jl = 2*qd + jj, jg = 8*tw + jl;
                if (jg < 15) {
                    const float tot = pbuf[0][tw][jl][c] + pbuf[1][tw][jl][c]
                                    + pbuf[2][tw][jl][c] + pbuf[3][tw][jl][c];
                    pooled[((n0 + tt)*16 + c)*3375 + dt*225 + ht*15 + jg]
                        = tot * (1.f/64.f);
                }
            }
        }
        if (tt < 7) {
            TRANSP(&xs[cur ^ 1][0]);             // write next tile's xs
            __syncthreads();                     // xs[cur^1] ready
        }
    }

    // ---- per-thread valid count (constant across tiles), x8 for 8 tiles
    float cnt1;
    if (inter) {
        cnt1 = owx ? 28.f : 32.f;
    } else {
        cnt1 = 0.f;
        const bool odok = !(dt == 15 && odq == 3);
        #pragma unroll
        for (int oh = 0; oh < 4; ++oh) {
            const bool ohok = !(ht == 15 && oh == 3);
            #pragma unroll
            for (int par = 0; par < 2; ++par)
                #pragma unroll
                for (int r = 0; r < 4; ++r) {
                    const bool owok = !(par == 1 && owx && r == 3);
                    cnt1 += (odok && ohok && owok) ? 1.f : 0.f;
                }
        }
    }
    const float cnt8 = 8.f * cnt1;
    // biased sums via closed form (once for all 8 tiles)
    float s_b  = fmaf(cnt8, bv, s_rawA);
    float sq_b = fmaf(fmaf(cnt8, bv, 2.f * s_rawA), bv, sq_rawA);

    s_b  += __shfl_xor(s_b, 16, 64);  s_b  += __shfl_xor(s_b, 32, 64);
    sq_b += __shfl_xor(sq_b, 16, 64); sq_b += __shfl_xor(sq_b, 32, 64);
    if (lane < 16) { sred[vv][lane] = s_b; qred[vv][lane] = sq_b; }
    __syncthreads();

    if (tid < 16) {
        const int blk = (bz*16 + dt)*16 + ht;    // [0,512)
        float S = 0.f, Q = 0.f;
        #pragma unroll
        for (int wv = 0; wv < 8; ++wv) { S += sred[wv][tid]; Q += qred[wv][tid]; }
        psum[tid*512 + blk] = S;
        psq [tid*512 + blk] = Q;
    }
}

__global__ void bnfinal(const float* __restrict__ psum, const float* __restrict__ psq,
                        const float* __restrict__ gamma, const float* __restrict__ beta,
                        const float* __restrict__ bias,
                        float* __restrict__ bn)
{
    const int co = blockIdx.x;
    const int t  = threadIdx.x;
    float S = 0, Q = 0;
    for (int blk = t; blk < 512; blk += 256) {
        S += psum[co*512 + blk];
        Q += psq [co*512 + blk];
    }
    #pragma unroll
    for (int off = 32; off > 0; off >>= 1) {
        S += __shfl_down(S, off, 64);
        Q += __shfl_down(Q, off, 64);
    }
    __shared__ float rs[4], rq[4];
    if ((t & 63) == 0) { rs[t >> 6] = S; rq[t >> 6] = Q; }
    __syncthreads();
    if (t == 0) {
        S = rs[0] + rs[1] + rs[2] + rs[3];
        Q = rq[0] + rq[1] + rq[2] + rq[3];
        const float cnt = 16.f * 63.f * 63.f * 63.f;
        const float mean = S / cnt;
        const float var  = Q / cnt - mean * mean;
        const float inv  = rsqrtf(var + 1e-5f);
        const float sc   = inv * gamma[co];
        bn[co]      = sc;
        // pooled stores RAW conv mean; bias enters the affine offset
        bn[16 + co] = beta[co] + (bias[co] - mean) * sc;
    }
}

__global__ void finalize(const float* __restrict__ pooled, const float* __restrict__ bn,
                         float* __restrict__ out)
{
    const int i  = blockIdx.x * 256 + threadIdx.x;   // 864000 = 3375*256
    const int co = (i / 3375) & 15;
    out[i] = pooled[i] * bn[co] + bn[16 + co];
}

extern "C" void kernel_launch(void* const* d_in, const int* in_sizes, int n_in,
                              void* d_out, int out_size, void* d_ws, size_t ws_size,
                              hipStream_t stream)
{
    const float* x     = (const float*)d_in[0];
    const float* w     = (const float*)d_in[1];
    const float* b     = (const float*)d_in[2];
    const float* gamma = (const float*)d_in[3];
    const float* beta  = (const float*)d_in[4];
    float* out = (float*)d_out;

    char* wsb = (char*)d_ws;
    unsigned short* wT = (unsigned short*)wsb;        // 27,648 B
    float* pooled = (float*)(wsb + 27648);            // 3,456,000 B
    float* psum   = (float*)(wsb + 27648 + 3456000);  // 32,768 B used
    float* psq    = (float*)(wsb + 27648 + 3456000 + 262144);
    float* bn     = (float*)(wsb + 27648 + 3456000 + 2*262144);

    kw<<<54, 256, 0, stream>>>(w, wT);
    dim3 grid(16, 16, 2);   // (ht, dt, n-octet)
    convf2<<<grid, 512, 0, stream>>>(x, wT, b, pooled, psum, psq);
    bnfinal<<<16, 256, 0, stream>>>(psum, psq, gamma, beta, b, bn);
    finalize<<<3375, 256, 0, stream>>>(pooled, bn, out);
}